// Round 4
// baseline (5053.213 us; speedup 1.0000x reference)
//
#include <hip/hip_runtime.h>
#include <math.h>

// Diffusion sampler: 49 sequential steps, rows independent.
// Round 4: 512 blocks x 512 threads, 8 rows/block (2 blocks/CU, 16 waves/CU),
// time-MLP + sigma schedule hoisted to a precompute kernel (-> d_ws),
// 3 barriers/step, logits via wave-shfl, categorical fused into G2 epilogue.
// All f32. PRNG: JAX threefry2x32, partitionable mode.

#define DXY 288
#define HID 256
#define NTHR 512
#define OUT_Y_OFF 1048576
#define OUT_T_OFF 1179648
#define CT_FLOATS (50 * 512)      // ws: Ct[t][k][c], t=1..49
#define STEP_OFF  CT_FLOATS       // ws: [stepf, sstep] pairs at STEP_OFF + 2*t

typedef unsigned int u32;

__device__ __forceinline__ void tf2x32(u32 k0, u32 k1, u32 x0, u32 x1, u32& o0, u32& o1) {
  u32 ks2 = k0 ^ k1 ^ 0x1BD11BDAu;
#define TFR(r) { x0 += x1; x1 = (x1 << (r)) | (x1 >> (32 - (r))); x1 ^= x0; }
  x0 += k0; x1 += k1;
  TFR(13) TFR(15) TFR(26) TFR(6)
  x0 += k1;  x1 += ks2 + 1u;
  TFR(17) TFR(29) TFR(16) TFR(24)
  x0 += ks2; x1 += k0 + 2u;
  TFR(13) TFR(15) TFR(26) TFR(6)
  x0 += k0;  x1 += k1 + 3u;
  TFR(17) TFR(29) TFR(16) TFR(24)
  x0 += k1;  x1 += ks2 + 4u;
  TFR(13) TFR(15) TFR(26) TFR(6)
  x0 += ks2; x1 += k0 + 5u;
#undef TFR
  o0 = x0; o1 = x1;
}

// partitionable random_bits for flat index j: x=(0,j), out = w0^w1
__device__ __forceinline__ u32 pbits(u32 ka, u32 kb, u32 j) {
  u32 w0, w1;
  tf2x32(ka, kb, 0u, j, w0, w1);
  return w0 ^ w1;
}

__device__ __forceinline__ float u01f(u32 bits) {
  union { u32 i; float f; } v;
  v.i = (bits >> 9) | 0x3F800000u;
  return v.f - 1.0f;
}

// XLA f32 ErfInv (Giles polynomial)
__device__ __forceinline__ float erfinv32(float x) {
  float w = -log1pf(-x * x);
  float p;
  if (w < 5.0f) {
    w -= 2.5f;
    p = 2.81022636e-08f;
    p = fmaf(p, w, 3.43273939e-07f);
    p = fmaf(p, w, -3.5233877e-06f);
    p = fmaf(p, w, -4.39150654e-06f);
    p = fmaf(p, w, 0.00021858087f);
    p = fmaf(p, w, -0.00125372503f);
    p = fmaf(p, w, -0.00417768164f);
    p = fmaf(p, w, 0.246640727f);
    p = fmaf(p, w, 1.50140941f);
  } else {
    w = sqrtf(w) - 3.0f;
    p = -0.000200214257f;
    p = fmaf(p, w, 0.000100950558f);
    p = fmaf(p, w, 0.00134934322f);
    p = fmaf(p, w, -0.00367342844f);
    p = fmaf(p, w, 0.00573950773f);
    p = fmaf(p, w, -0.0076224613f);
    p = fmaf(p, w, 0.00943887047f);
    p = fmaf(p, w, 1.00167406f);
    p = fmaf(p, w, 2.83297682f);
  }
  return p * x;
}

__device__ __forceinline__ float nrmf(u32 bits) {
  float val = fmaf(u01f(bits), 2.0f, -0.99999994f);
  return 1.41421356f * erfinv32(val);
}
__device__ __forceinline__ float gumf(u32 bits) {
  float u = fmaxf(u01f(bits), 1.17549435e-38f);
  return -logf(-logf(u));
}
__device__ __forceinline__ float siluf(float x) {
  return x / (1.0f + expf(-x));
}
__device__ __forceinline__ void fma4(float a, const float4& b, float* acc) {
  acc[0] = fmaf(a, b.x, acc[0]);
  acc[1] = fmaf(a, b.y, acc[1]);
  acc[2] = fmaf(a, b.z, acc[2]);
  acc[3] = fmaf(a, b.w, acc[3]);
}

// ---- precompute: Ct[t][k][c] = b1[c] + te[k]@W1b + (time_mlp(tau_t))@W1c, and step scalars ----
__global__ void precompute_ct(
    const float* __restrict__ t_embed,
    const float* __restrict__ tm_w1, const float* __restrict__ tm_b1,
    const float* __restrict__ tm_w2, const float* __restrict__ tm_b2,
    const float* __restrict__ tr_w1, const float* __restrict__ tr_b1,
    float* __restrict__ ws)
{
  const int t = blockIdx.x + 1;       // 1..49
  const int c = threadIdx.x;          // 0..255
  __shared__ float tmpre[HID];
  __shared__ float tmv[HID];
  const float tau = (float)t / 50.0f;

  tmpre[c] = siluf(fmaf(tau, tm_w1[c], tm_b1[c]));
  __syncthreads();
  {
    float acc = tm_b2[c];
    for (int i = 0; i < HID; i++)
      acc = fmaf(tmpre[i], tm_w2[i * HID + c], acc);
    tmv[c] = acc;
  }
  __syncthreads();
  float D = 0.f;
  for (int i = 0; i < HID; i++)
    D = fmaf(tmv[i], tr_w1[(544 + i) * HID + c], D);
  float ce0 = tr_b1[c], ce1 = tr_b1[c];
  for (int i = 0; i < HID; i++) {
    ce0 = fmaf(t_embed[i], tr_w1[(288 + i) * HID + c], ce0);
    ce1 = fmaf(t_embed[HID + i], tr_w1[(288 + i) * HID + c], ce1);
  }
  ws[t * 512 + c] = ce0 + D;
  ws[t * 512 + 256 + c] = ce1 + D;

  if (c == 0) {
    const double lt = 6.214608098422191;  // ln 500
    float sig_t = (float)(0.002 * exp(((double)t / 50.0) * lt));
    float sig_p = (float)(0.002 * exp(((double)(t - 1) / 50.0) * lt));
    float stepf = sig_t * sig_t - sig_p * sig_p;
    ws[STEP_OFF + 2 * t] = stepf;
    ws[STEP_OFF + 2 * t + 1] = sqrtf(stepf);
  }
}

// ---- main sampler ----
__global__ __launch_bounds__(NTHR, 4) void sampler_k(
    const float* __restrict__ xy0, const int* __restrict__ t0,
    const float* __restrict__ tr_w1,
    const float* __restrict__ tr_w2, const float* __restrict__ tr_b2,
    const float* __restrict__ sh_w, const float* __restrict__ sh_b,
    const float* __restrict__ ch_w, const float* __restrict__ ch_b,
    const float* __restrict__ ws,
    float* __restrict__ out)
{
  __shared__ float xy_s[8][DXY];      // 9.2 KB
  __shared__ float h1_s[8][HID];      // 8.2 KB
  __shared__ float h2_s[8][HID];      // 8.2 KB
  __shared__ float ct_s[2][HID];      // 2 KB
  __shared__ int tcur[8];

  const int tid = threadIdx.x;
  const int row0 = blockIdx.x * 8;    // block owns rows [row0, row0+8)
  const int row = tid >> 6;           // one wave per row
  const int lane = tid & 63;
  const int c0 = lane * 4;

  // load xy (rows contiguous -> flat float4 copy)
  {
    const float4* src = (const float4*)(xy0 + row0 * DXY);
    float4* dst = (float4*)&xy_s[0][0];
    for (int idx = tid; idx < 8 * DXY / 4; idx += NTHR) dst[idx] = src[idx];
  }
  if (tid < 8) tcur[tid] = t0[row0 + tid];

  // hoisted constants
  float chw0[4], chw1[4];
  #pragma unroll
  for (int j = 0; j < 4; j++) {
    chw0[j] = ch_w[(c0 + j) * 2 + 0];
    chw1[j] = ch_w[(c0 + j) * 2 + 1];
  }
  const float4 b2r = *(const float4*)(tr_b2 + c0);
  const float cb0 = ch_b[0], cb1 = ch_b[1];
  float sbr[5];
  #pragma unroll
  for (int u = 0; u < 5; u++)
    if (!(u == 4 && lane >= 32)) sbr[u] = sh_b[lane + 64 * u];

  #pragma unroll 1
  for (int t_idx = 49; t_idx >= 1; --t_idx) {
    // per-step scalars from ws (uniform; L2-hit)
    const float stepf = ws[STEP_OFF + 2 * t_idx];
    const float sstep = ws[STEP_OFF + 2 * t_idx + 1];

    // keys (uniform -> scalarized by compiler)
    u32 f0, f1, k1a, k1b, k2a, k2b;
    tf2x32(0u, 42u, 0u, (u32)t_idx, f0, f1);
    tf2x32(f0, f1, 0u, 0u, k1a, k1b);
    tf2x32(f0, f1, 0u, 1u, k2a, k2b);

    // Ct -> LDS (512 floats, one per thread)
    ((float*)ct_s)[tid] = ws[t_idx * 512 + tid];
    __syncthreads();   // B1: ct ready; prev-step xy_s/tcur writes visible

    // ---- G1: h1[row][c0..c0+3] = silu(xy[row] @ W1[0:288] + Ct[tcur[row]]) ----
    {
      float acc[4] = {0.f, 0.f, 0.f, 0.f};
      const float* wp = tr_w1 + c0;
      for (int i = 0; i < DXY; i += 4) {
        float4 a = *(const float4*)&xy_s[row][i];     // wave-uniform broadcast
        float4 b0 = *(const float4*)(wp + (i + 0) * HID);
        float4 b1 = *(const float4*)(wp + (i + 1) * HID);
        float4 b2 = *(const float4*)(wp + (i + 2) * HID);
        float4 b3 = *(const float4*)(wp + (i + 3) * HID);
        fma4(a.x, b0, acc); fma4(a.y, b1, acc); fma4(a.z, b2, acc); fma4(a.w, b3, acc);
      }
      const int tc = tcur[row];
      const float4 ct = *(const float4*)&ct_s[tc][c0];
      float4 o;
      o.x = siluf(acc[0] + ct.x);
      o.y = siluf(acc[1] + ct.y);
      o.z = siluf(acc[2] + ct.z);
      o.w = siluf(acc[3] + ct.w);
      *(float4*)&h1_s[row][c0] = o;
    }
    __syncthreads();   // B2: h1 ready

    // ---- G2: h2 = silu(h1 @ W2 + b2); logits via wave shfl; categorical ----
    {
      float acc[4] = {0.f, 0.f, 0.f, 0.f};
      const float* wp = tr_w2 + c0;
      for (int i = 0; i < HID; i += 4) {
        float4 a = *(const float4*)&h1_s[row][i];
        float4 b0 = *(const float4*)(wp + (i + 0) * HID);
        float4 b1 = *(const float4*)(wp + (i + 1) * HID);
        float4 b2 = *(const float4*)(wp + (i + 2) * HID);
        float4 b3 = *(const float4*)(wp + (i + 3) * HID);
        fma4(a.x, b0, acc); fma4(a.y, b1, acc); fma4(a.z, b2, acc); fma4(a.w, b3, acc);
      }
      float4 h2v;
      h2v.x = siluf(acc[0] + b2r.x);
      h2v.y = siluf(acc[1] + b2r.y);
      h2v.z = siluf(acc[2] + b2r.z);
      h2v.w = siluf(acc[3] + b2r.w);

      // logit partials from registers
      float p0 = h2v.x * chw0[0] + h2v.y * chw0[1] + h2v.z * chw0[2] + h2v.w * chw0[3];
      float p1 = h2v.x * chw1[0] + h2v.y * chw1[1] + h2v.z * chw1[2] + h2v.w * chw1[3];
      #pragma unroll
      for (int off = 32; off > 0; off >>= 1) {
        p0 += __shfl_down(p0, off);
        p1 += __shfl_down(p1, off);
      }
      if (lane == 0) {
        float l0 = p0 + cb0, l1 = p1 + cb1;
        u32 j = (u32)(row0 + row) * 2u;
        float g0 = gumf(pbits(k2a, k2b, j));
        float g1 = gumf(pbits(k2a, k2b, j + 1u));
        tcur[row] = (l1 + g1 > l0 + g0) ? 1 : 0;
      }
      *(float4*)&h2_s[row][c0] = h2v;
    }
    __syncthreads();   // B3: h2 ready (tcur visible by next B1)

    // ---- G3: score = h2 @ sh_w + sh_b; xy += step*score + sqrt(step)*noise ----
    {
      float acc[5] = {0.f, 0.f, 0.f, 0.f, 0.f};
      for (int i = 0; i < HID; i += 4) {
        float4 a = *(const float4*)&h2_s[row][i];
        #pragma unroll
        for (int u = 0; u < 5; u++) {
          if (u == 4 && lane >= 32) continue;
          const float* bp = sh_w + i * DXY + lane + 64 * u;
          float w0 = bp[0];
          float w1 = bp[DXY];
          float w2 = bp[2 * DXY];
          float w3 = bp[3 * DXY];
          acc[u] = fmaf(a.x, w0, fmaf(a.y, w1, fmaf(a.z, w2, fmaf(a.w, w3, acc[u]))));
        }
      }
      const u32 gr = (u32)(row0 + row);
      #pragma unroll
      for (int u = 0; u < 5; u++) {
        if (u == 4 && lane >= 32) continue;
        int c = lane + 64 * u;
        float sc = acc[u] + sbr[u];
        float n = nrmf(pbits(k1a, k1b, gr * 288u + (u32)c));
        xy_s[row][c] = fmaf(sstep, n, fmaf(stepf, sc, xy_s[row][c]));
      }
    }
    // no barrier here; next step's B1 covers xy_s hazard
  }
  __syncthreads();

  // ---- final store: x (4096x256), y (4096x32), t (4096) ----
  for (int idx = tid; idx < 8 * DXY; idx += NTHR) {
    int L = idx / DXY;
    int c = idx - L * DXY;
    int r = row0 + L;
    float v = xy_s[L][c];
    if (c < 256) out[r * 256 + c] = v;
    else out[OUT_Y_OFF + r * 32 + (c - 256)] = v;
  }
  if (tid < 8) out[OUT_T_OFF + row0 + tid] = (float)tcur[tid];
}

extern "C" void kernel_launch(void* const* d_in, const int* in_sizes, int n_in,
                              void* d_out, int out_size, void* d_ws, size_t ws_size,
                              hipStream_t stream) {
  (void)in_sizes; (void)n_in; (void)ws_size; (void)out_size;
  const float* xy0     = (const float*)d_in[0];
  const int*   t0      = (const int*)d_in[1];
  const float* t_embed = (const float*)d_in[2];
  const float* tm_w1   = (const float*)d_in[3];
  const float* tm_b1   = (const float*)d_in[4];
  const float* tm_w2   = (const float*)d_in[5];
  const float* tm_b2   = (const float*)d_in[6];
  const float* tr_w1   = (const float*)d_in[7];
  const float* tr_b1   = (const float*)d_in[8];
  const float* tr_w2   = (const float*)d_in[9];
  const float* tr_b2   = (const float*)d_in[10];
  const float* sh_w    = (const float*)d_in[11];
  const float* sh_b    = (const float*)d_in[12];
  const float* ch_w    = (const float*)d_in[13];
  const float* ch_b    = (const float*)d_in[14];
  float* ws  = (float*)d_ws;
  float* out = (float*)d_out;

  precompute_ct<<<49, 256, 0, stream>>>(t_embed, tm_w1, tm_b1, tm_w2, tm_b2,
                                        tr_w1, tr_b1, ws);
  sampler_k<<<512, NTHR, 0, stream>>>(xy0, t0, tr_w1, tr_w2, tr_b2,
                                      sh_w, sh_b, ch_w, ch_b, ws, out);
}

// Round 5
// 2721.456 us; speedup vs baseline: 1.8568x; 1.8568x over previous
//
#include <hip/hip_runtime.h>
#include <math.h>

// Diffusion sampler: 49 sequential steps, rows independent.
// Round 5: 256 blocks x 512 threads, 16 rows/block, rows are WAVE-PRIVATE
// (wave w owns rows {w, w+8}) -> ZERO barriers in the step loop.
// Time-MLP + sigma schedule precomputed into d_ws. All f32.
// PRNG: JAX threefry2x32, partitionable mode.

#define DXY 288
#define HID 256
#define NTHR 512
#define OUT_Y_OFF 1048576
#define OUT_T_OFF 1179648
#define CT_FLOATS (50 * 512)
#define STEP_OFF  CT_FLOATS

typedef unsigned int u32;

__device__ __forceinline__ void tf2x32(u32 k0, u32 k1, u32 x0, u32 x1, u32& o0, u32& o1) {
  u32 ks2 = k0 ^ k1 ^ 0x1BD11BDAu;
#define TFR(r) { x0 += x1; x1 = (x1 << (r)) | (x1 >> (32 - (r))); x1 ^= x0; }
  x0 += k0; x1 += k1;
  TFR(13) TFR(15) TFR(26) TFR(6)
  x0 += k1;  x1 += ks2 + 1u;
  TFR(17) TFR(29) TFR(16) TFR(24)
  x0 += ks2; x1 += k0 + 2u;
  TFR(13) TFR(15) TFR(26) TFR(6)
  x0 += k0;  x1 += k1 + 3u;
  TFR(17) TFR(29) TFR(16) TFR(24)
  x0 += k1;  x1 += ks2 + 4u;
  TFR(13) TFR(15) TFR(26) TFR(6)
  x0 += ks2; x1 += k0 + 5u;
#undef TFR
  o0 = x0; o1 = x1;
}

__device__ __forceinline__ u32 pbits(u32 ka, u32 kb, u32 j) {
  u32 w0, w1;
  tf2x32(ka, kb, 0u, j, w0, w1);
  return w0 ^ w1;
}

__device__ __forceinline__ float u01f(u32 bits) {
  union { u32 i; float f; } v;
  v.i = (bits >> 9) | 0x3F800000u;
  return v.f - 1.0f;
}

// XLA f32 ErfInv (Giles polynomial)
__device__ __forceinline__ float erfinv32(float x) {
  float w = -log1pf(-x * x);
  float p;
  if (w < 5.0f) {
    w -= 2.5f;
    p = 2.81022636e-08f;
    p = fmaf(p, w, 3.43273939e-07f);
    p = fmaf(p, w, -3.5233877e-06f);
    p = fmaf(p, w, -4.39150654e-06f);
    p = fmaf(p, w, 0.00021858087f);
    p = fmaf(p, w, -0.00125372503f);
    p = fmaf(p, w, -0.00417768164f);
    p = fmaf(p, w, 0.246640727f);
    p = fmaf(p, w, 1.50140941f);
  } else {
    w = sqrtf(w) - 3.0f;
    p = -0.000200214257f;
    p = fmaf(p, w, 0.000100950558f);
    p = fmaf(p, w, 0.00134934322f);
    p = fmaf(p, w, -0.00367342844f);
    p = fmaf(p, w, 0.00573950773f);
    p = fmaf(p, w, -0.0076224613f);
    p = fmaf(p, w, 0.00943887047f);
    p = fmaf(p, w, 1.00167406f);
    p = fmaf(p, w, 2.83297682f);
  }
  return p * x;
}

__device__ __forceinline__ float nrmf(u32 bits) {
  float val = fmaf(u01f(bits), 2.0f, -0.99999994f);
  return 1.41421356f * erfinv32(val);
}
__device__ __forceinline__ float gumf(u32 bits) {
  float u = fmaxf(u01f(bits), 1.17549435e-38f);
  return -logf(-logf(u));
}
__device__ __forceinline__ float siluf(float x) {
  return x / (1.0f + expf(-x));
}
__device__ __forceinline__ void fma4(float a, const float4& b, float* acc) {
  acc[0] = fmaf(a, b.x, acc[0]);
  acc[1] = fmaf(a, b.y, acc[1]);
  acc[2] = fmaf(a, b.z, acc[2]);
  acc[3] = fmaf(a, b.w, acc[3]);
}

// ---- precompute: Ct[t][k][c] and step scalars into ws ----
__global__ void precompute_ct(
    const float* __restrict__ t_embed,
    const float* __restrict__ tm_w1, const float* __restrict__ tm_b1,
    const float* __restrict__ tm_w2, const float* __restrict__ tm_b2,
    const float* __restrict__ tr_w1, const float* __restrict__ tr_b1,
    float* __restrict__ ws)
{
  const int t = blockIdx.x + 1;       // 1..49
  const int c = threadIdx.x;          // 0..255
  __shared__ float tmpre[HID];
  __shared__ float tmv[HID];
  const float tau = (float)t / 50.0f;

  tmpre[c] = siluf(fmaf(tau, tm_w1[c], tm_b1[c]));
  __syncthreads();
  {
    float acc = tm_b2[c];
    for (int i = 0; i < HID; i++)
      acc = fmaf(tmpre[i], tm_w2[i * HID + c], acc);
    tmv[c] = acc;
  }
  __syncthreads();
  float D = 0.f;
  for (int i = 0; i < HID; i++)
    D = fmaf(tmv[i], tr_w1[(544 + i) * HID + c], D);
  float ce0 = tr_b1[c], ce1 = tr_b1[c];
  for (int i = 0; i < HID; i++) {
    ce0 = fmaf(t_embed[i], tr_w1[(288 + i) * HID + c], ce0);
    ce1 = fmaf(t_embed[HID + i], tr_w1[(288 + i) * HID + c], ce1);
  }
  ws[t * 512 + c] = ce0 + D;
  ws[t * 512 + 256 + c] = ce1 + D;

  if (c == 0) {
    const double lt = 6.214608098422191;  // ln 500
    float sig_t = (float)(0.002 * exp(((double)t / 50.0) * lt));
    float sig_p = (float)(0.002 * exp(((double)(t - 1) / 50.0) * lt));
    float stepf = sig_t * sig_t - sig_p * sig_p;
    ws[STEP_OFF + 2 * t] = stepf;
    ws[STEP_OFF + 2 * t + 1] = sqrtf(stepf);
  }
}

// ---- main sampler: barrier-free, wave-private rows ----
__global__ __launch_bounds__(NTHR, 2) void sampler_k(
    const float* __restrict__ xy0, const int* __restrict__ t0,
    const float* __restrict__ tr_w1,
    const float* __restrict__ tr_w2, const float* __restrict__ tr_b2,
    const float* __restrict__ sh_w, const float* __restrict__ sh_b,
    const float* __restrict__ ch_w, const float* __restrict__ ch_b,
    const float* __restrict__ ws,
    float* __restrict__ out)
{
  __shared__ float xy_s[16][DXY];   // 18.4 KB, rows wave-private
  __shared__ float h_s[16][HID];    // 16.4 KB, h1 then h2 (same-wave in-order LDS)

  const int tid = threadIdx.x;
  const int lane = tid & 63;
  const int w = tid >> 6;           // wave id, owns rows {w, w+8}
  const int rA = w, rB = w + 8;
  const int row0 = blockIdx.x * 16;
  const int gA = row0 + rA, gB = row0 + rB;
  const int c0 = lane * 4;
  const bool xl = (lane < 8);
  const int cX = 256 + lane * 4;    // extra quad for lanes 0..7

  // ---- load xy rows (wave-local) ----
  {
    const float4* sA = (const float4*)(xy0 + gA * DXY);
    const float4* sB = (const float4*)(xy0 + gB * DXY);
    *(float4*)&xy_s[rA][c0] = sA[lane];
    *(float4*)&xy_s[rB][c0] = sB[lane];
    if (xl) {
      *(float4*)&xy_s[rA][cX] = sA[64 + lane];
      *(float4*)&xy_s[rB][cX] = sB[64 + lane];
    }
  }
  int tcA = t0[gA];                 // broadcast loads, uniform per wave
  int tcB = t0[gB];

  // ---- hoisted constants ----
  float chw0[4], chw1[4];
  #pragma unroll
  for (int j = 0; j < 4; j++) {
    chw0[j] = ch_w[(c0 + j) * 2 + 0];
    chw1[j] = ch_w[(c0 + j) * 2 + 1];
  }
  const float4 b2r = *(const float4*)(tr_b2 + c0);
  const float cb0 = ch_b[0], cb1 = ch_b[1];
  const float4 sbm = *(const float4*)(sh_b + c0);
  const int cEx = 256 + (lane & 31);       // scalar extra col (all 64 lanes)
  const int rEx = (lane < 32) ? rA : rB;
  const u32 gEx = (u32)(row0 + rEx);
  const float sbEx = sh_b[cEx];

  #pragma unroll 1
  for (int t_idx = 49; t_idx >= 1; --t_idx) {
    const float stepf = ws[STEP_OFF + 2 * t_idx];
    const float sstep = ws[STEP_OFF + 2 * t_idx + 1];

    u32 f0, f1, k1a, k1b, k2a, k2b;
    tf2x32(0u, 42u, 0u, (u32)t_idx, f0, f1);
    tf2x32(f0, f1, 0u, 0u, k1a, k1b);
    tf2x32(f0, f1, 0u, 1u, k2a, k2b);

    // Ct rows for current t (t-embedding + time-mlp, precomputed)
    const float* ct = ws + t_idx * 512;
    const float4 ctA = *(const float4*)(ct + tcA * 256 + c0);
    const float4 ctB = *(const float4*)(ct + tcB * 256 + c0);

    // ---- G1: h1 = silu(xy @ W1[0:288] + Ct) ----
    {
      float aA[4] = {0.f, 0.f, 0.f, 0.f};
      float aB[4] = {0.f, 0.f, 0.f, 0.f};
      const float* wp = tr_w1 + c0;
      #pragma unroll 4
      for (int i = 0; i < DXY; i += 4) {
        float4 xA = *(const float4*)&xy_s[rA][i];
        float4 xB = *(const float4*)&xy_s[rB][i];
        float4 b0 = *(const float4*)(wp + (i + 0) * HID);
        float4 b1 = *(const float4*)(wp + (i + 1) * HID);
        float4 b2 = *(const float4*)(wp + (i + 2) * HID);
        float4 b3 = *(const float4*)(wp + (i + 3) * HID);
        fma4(xA.x, b0, aA); fma4(xA.y, b1, aA); fma4(xA.z, b2, aA); fma4(xA.w, b3, aA);
        fma4(xB.x, b0, aB); fma4(xB.y, b1, aB); fma4(xB.z, b2, aB); fma4(xB.w, b3, aB);
      }
      float4 oA, oB;
      oA.x = siluf(aA[0] + ctA.x); oA.y = siluf(aA[1] + ctA.y);
      oA.z = siluf(aA[2] + ctA.z); oA.w = siluf(aA[3] + ctA.w);
      oB.x = siluf(aB[0] + ctB.x); oB.y = siluf(aB[1] + ctB.y);
      oB.z = siluf(aB[2] + ctB.z); oB.w = siluf(aB[3] + ctB.w);
      *(float4*)&h_s[rA][c0] = oA;
      *(float4*)&h_s[rB][c0] = oB;
    }

    // ---- G2: h2 = silu(h1 @ W2 + b2); logits; categorical ----
    {
      float aA[4] = {0.f, 0.f, 0.f, 0.f};
      float aB[4] = {0.f, 0.f, 0.f, 0.f};
      const float* wp = tr_w2 + c0;
      #pragma unroll 4
      for (int i = 0; i < HID; i += 4) {
        float4 hA = *(const float4*)&h_s[rA][i];
        float4 hB = *(const float4*)&h_s[rB][i];
        float4 b0 = *(const float4*)(wp + (i + 0) * HID);
        float4 b1 = *(const float4*)(wp + (i + 1) * HID);
        float4 b2 = *(const float4*)(wp + (i + 2) * HID);
        float4 b3 = *(const float4*)(wp + (i + 3) * HID);
        fma4(hA.x, b0, aA); fma4(hA.y, b1, aA); fma4(hA.z, b2, aA); fma4(hA.w, b3, aA);
        fma4(hB.x, b0, aB); fma4(hB.y, b1, aB); fma4(hB.z, b2, aB); fma4(hB.w, b3, aB);
      }
      float4 hA2, hB2;
      hA2.x = siluf(aA[0] + b2r.x); hA2.y = siluf(aA[1] + b2r.y);
      hA2.z = siluf(aA[2] + b2r.z); hA2.w = siluf(aA[3] + b2r.w);
      hB2.x = siluf(aB[0] + b2r.x); hB2.y = siluf(aB[1] + b2r.y);
      hB2.z = siluf(aB[2] + b2r.z); hB2.w = siluf(aB[3] + b2r.w);
      // write h2 (in-place after all h1 reads; same-wave LDS is in-order)
      *(float4*)&h_s[rA][c0] = hA2;
      *(float4*)&h_s[rB][c0] = hB2;

      // logits partials
      float pA0 = hA2.x * chw0[0] + hA2.y * chw0[1] + hA2.z * chw0[2] + hA2.w * chw0[3];
      float pA1 = hA2.x * chw1[0] + hA2.y * chw1[1] + hA2.z * chw1[2] + hA2.w * chw1[3];
      float pB0 = hB2.x * chw0[0] + hB2.y * chw0[1] + hB2.z * chw0[2] + hB2.w * chw0[3];
      float pB1 = hB2.x * chw1[0] + hB2.y * chw1[1] + hB2.z * chw1[2] + hB2.w * chw1[3];
      #pragma unroll
      for (int off = 32; off > 0; off >>= 1) {
        pA0 += __shfl_xor(pA0, off);
        pA1 += __shfl_xor(pA1, off);
        pB0 += __shfl_xor(pB0, off);
        pB1 += __shfl_xor(pB1, off);
      }
      // gumbels: lane&3 -> (rowA/rowB, class0/1); divergence-free
      u32 grow = (lane & 2) ? (u32)gB : (u32)gA;
      float g = gumf(pbits(k2a, k2b, grow * 2u + (u32)(lane & 1)));
      float g0 = __shfl(g, 0), g1 = __shfl(g, 1);
      float g2 = __shfl(g, 2), g3 = __shfl(g, 3);
      tcA = (pA1 + cb1 + g1 > pA0 + cb0 + g0) ? 1 : 0;
      tcB = (pB1 + cb1 + g3 > pB0 + cb0 + g2) ? 1 : 0;
    }

    // ---- G3 main: score cols 0..255 (float4/lane) ----
    {
      float sA[4] = {0.f, 0.f, 0.f, 0.f};
      float sB[4] = {0.f, 0.f, 0.f, 0.f};
      #pragma unroll 4
      for (int i = 0; i < HID; i += 4) {
        float4 hA = *(const float4*)&h_s[rA][i];
        float4 hB = *(const float4*)&h_s[rB][i];
        const float* bp = sh_w + i * DXY + c0;
        float4 b0 = *(const float4*)(bp);
        float4 b1 = *(const float4*)(bp + DXY);
        float4 b2 = *(const float4*)(bp + 2 * DXY);
        float4 b3 = *(const float4*)(bp + 3 * DXY);
        fma4(hA.x, b0, sA); fma4(hA.y, b1, sA); fma4(hA.z, b2, sA); fma4(hA.w, b3, sA);
        fma4(hB.x, b0, sB); fma4(hB.y, b1, sB); fma4(hB.z, b2, sB); fma4(hB.w, b3, sB);
      }
      const u32 jA = (u32)gA * 288u + (u32)c0;
      const u32 jB = (u32)gB * 288u + (u32)c0;
      float4 xA = *(const float4*)&xy_s[rA][c0];
      float4 xB = *(const float4*)&xy_s[rB][c0];
      xA.x = fmaf(sstep, nrmf(pbits(k1a, k1b, jA + 0u)), fmaf(stepf, sA[0] + sbm.x, xA.x));
      xA.y = fmaf(sstep, nrmf(pbits(k1a, k1b, jA + 1u)), fmaf(stepf, sA[1] + sbm.y, xA.y));
      xA.z = fmaf(sstep, nrmf(pbits(k1a, k1b, jA + 2u)), fmaf(stepf, sA[2] + sbm.z, xA.z));
      xA.w = fmaf(sstep, nrmf(pbits(k1a, k1b, jA + 3u)), fmaf(stepf, sA[3] + sbm.w, xA.w));
      xB.x = fmaf(sstep, nrmf(pbits(k1a, k1b, jB + 0u)), fmaf(stepf, sB[0] + sbm.x, xB.x));
      xB.y = fmaf(sstep, nrmf(pbits(k1a, k1b, jB + 1u)), fmaf(stepf, sB[1] + sbm.y, xB.y));
      xB.z = fmaf(sstep, nrmf(pbits(k1a, k1b, jB + 2u)), fmaf(stepf, sB[2] + sbm.z, xB.z));
      xB.w = fmaf(sstep, nrmf(pbits(k1a, k1b, jB + 3u)), fmaf(stepf, sB[3] + sbm.w, xB.w));
      *(float4*)&xy_s[rA][c0] = xA;
      *(float4*)&xy_s[rB][c0] = xB;
    }

    // ---- G3 extra: cols 256..287 x 2 rows = 64 scalar outputs (1/lane) ----
    {
      float sE = 0.f;
      #pragma unroll 4
      for (int i = 0; i < HID; i += 4) {
        float4 hE = *(const float4*)&h_s[rEx][i];
        const float* bp = sh_w + i * DXY + cEx;
        sE = fmaf(hE.x, bp[0],
             fmaf(hE.y, bp[DXY],
             fmaf(hE.z, bp[2 * DXY],
             fmaf(hE.w, bp[3 * DXY], sE))));
      }
      u32 jE = gEx * 288u + (u32)cEx;
      float nE = nrmf(pbits(k1a, k1b, jE));
      xy_s[rEx][cEx] = fmaf(sstep, nE, fmaf(stepf, sE + sbEx, xy_s[rEx][cEx]));
    }
  }

  // ---- final store (wave-local rows): x, y, t ----
  {
    float4 vA = *(const float4*)&xy_s[rA][c0];
    float4 vB = *(const float4*)&xy_s[rB][c0];
    *(float4*)(out + gA * 256 + c0) = vA;
    *(float4*)(out + gB * 256 + c0) = vB;
    if (xl) {
      float4 yA = *(const float4*)&xy_s[rA][cX];
      float4 yB = *(const float4*)&xy_s[rB][cX];
      *(float4*)(out + OUT_Y_OFF + gA * 32 + lane * 4) = yA;
      *(float4*)(out + OUT_Y_OFF + gB * 32 + lane * 4) = yB;
    }
    if (lane == 0) {
      out[OUT_T_OFF + gA] = (float)tcA;
      out[OUT_T_OFF + gB] = (float)tcB;
    }
  }
}

extern "C" void kernel_launch(void* const* d_in, const int* in_sizes, int n_in,
                              void* d_out, int out_size, void* d_ws, size_t ws_size,
                              hipStream_t stream) {
  (void)in_sizes; (void)n_in; (void)ws_size; (void)out_size;
  const float* xy0     = (const float*)d_in[0];
  const int*   t0      = (const int*)d_in[1];
  const float* t_embed = (const float*)d_in[2];
  const float* tm_w1   = (const float*)d_in[3];
  const float* tm_b1   = (const float*)d_in[4];
  const float* tm_w2   = (const float*)d_in[5];
  const float* tm_b2   = (const float*)d_in[6];
  const float* tr_w1   = (const float*)d_in[7];
  const float* tr_b1   = (const float*)d_in[8];
  const float* tr_w2   = (const float*)d_in[9];
  const float* tr_b2   = (const float*)d_in[10];
  const float* sh_w    = (const float*)d_in[11];
  const float* sh_b    = (const float*)d_in[12];
  const float* ch_w    = (const float*)d_in[13];
  const float* ch_b    = (const float*)d_in[14];
  float* ws  = (float*)d_ws;
  float* out = (float*)d_out;

  precompute_ct<<<49, 256, 0, stream>>>(t_embed, tm_w1, tm_b1, tm_w2, tm_b2,
                                        tr_w1, tr_b1, ws);
  sampler_k<<<256, NTHR, 0, stream>>>(xy0, t0, tr_w1, tr_w2, tr_b2,
                                      sh_w, sh_b, ch_w, ch_b, ws, out);
}